// Round 5
// baseline (23959.482 us; speedup 1.0000x reference)
//
#include <hip/hip_runtime.h>
#include <math.h>

// Persistent-kernel LSTM: H=2048, SEQ=4096, fp32 (no fp32 MFMA -> vector ALU).
// 256 WGs x 512 thr, 1 WG/CU. Wave w of WG g owns hidden unit k=g*8+w; each
// lane holds 4 gate-rows x 32 cols of W_hh (128 floats, VGPR/AGPR unified).
//
// Cross-step exchange v3 (self-validating data, 1-barrier steps):
//   hval[2][2048] fp32 where the low 8 mantissa bits of each value are the
//   step tag (t+1)&0xFF. Producer wave lane0 fires ONE relaxed agent store
//   (no drain, no flag). Consumer thread tid polls its 4 contiguous values
//   hval[slot][4*tid..4*tid+4) -- the poll IS the data load. Slot parity +
//   lockstep (max 2-step spread) makes the 8-bit tag ABA-safe; tag-dirty
//   low bits are kept (error ~2^-15 relative, negligible).
// y_{t-2} drained by WG0/tid0 each step from LDS partials. d_ws: 16 KB.

#define HDIM 2048
#define SEQ 4096
#define NWG 256
#define TPB 512

__device__ __forceinline__ float sigmoidf_(float x) {
  return 1.0f / (1.0f + expf(-x));
}
__device__ __forceinline__ float tanh_(float x) {
  float e = expf(-2.0f * fabsf(x));
  float r = (1.0f - e) / (1.0f + e);
  return copysignf(r, x);
}

// slot 1 = h_{-1}: value 0.0f with tag 0 -> bit pattern 0
__global__ void lstm_init(unsigned* hval) {
  const int i = blockIdx.x * 256 + threadIdx.x;   // 8 blocks x 256 = 2048
  hval[HDIM + i] = 0u;
}

__global__ __launch_bounds__(TPB, 2) void lstm_persist(
    const float* __restrict__ x, const float* __restrict__ w_ih,
    const float* __restrict__ w_hh, const float* __restrict__ b_ih,
    const float* __restrict__ b_hh, const float* __restrict__ w_out,
    const float* __restrict__ b_out, float* __restrict__ out,
    unsigned* __restrict__ hval)
{
  const int wg   = blockIdx.x;
  const int tid  = threadIdx.x;
  const int wave = tid >> 6;
  const int lane = tid & 63;
  const int k    = wg * 8 + wave;   // this wave's hidden unit

  __shared__ float xs[SEQ];        // 16 KB
  __shared__ float hs[2][HDIM];    // 16 KB, double-buffered
  __shared__ float wys[2][8];      // per-wave y partials, double-buffered

  // ---- one-time: weights into registers ----
  // rows g=0..3 (gates i,f,g,o of unit k): row = k + g*HDIM
  // cols per lane: {256*j + 4*lane + q}, j=0..7, q=0..3  -> 32 float4
  float4 W[32];
  float wx[4], bb[4];
  #pragma unroll
  for (int g = 0; g < 4; ++g) {
    const int row = k + g * HDIM;
    const float* rp = w_hh + (size_t)row * HDIM + lane * 4;
    #pragma unroll
    for (int j = 0; j < 8; ++j)
      W[g * 8 + j] = *(const float4*)(rp + j * 256);
    wx[g] = w_ih[row];
    bb[g] = b_ih[row] + b_hh[row];
  }
  // consumer slice: 4 contiguous units [4*tid, 4*tid+4)
  float wo[4];
  #pragma unroll
  for (int q = 0; q < 4; ++q) wo[q] = w_out[4 * tid + q];
  const float bout = b_out[0];

  for (int i = tid; i < SEQ; i += TPB) xs[i] = x[i];

  float cc = 0.f, hh = 0.f;
  float hv[4];
  __syncthreads();

  for (int t = 0; t < SEQ; ++t) {
    const int par = t & 1;

    // ---- poll h_{t-1}: 4 contiguous values, tag byte == t&0xFF ----
    const unsigned want = (unsigned)t & 0xFFu;
    const unsigned* src = hval + (par ^ 1) * HDIM + 4 * tid;
    unsigned v[4];
    unsigned mask = 0xFu;
    int guard = 0;
    for (;;) {
      #pragma unroll
      for (int q = 0; q < 4; ++q)
        if (mask & (1u << q))
          v[q] = __hip_atomic_load(&src[q], __ATOMIC_RELAXED,
                                   __HIP_MEMORY_SCOPE_AGENT);
      #pragma unroll
      for (int q = 0; q < 4; ++q)
        if ((mask & (1u << q)) && (v[q] & 0xFFu) == want)
          mask &= ~(1u << q);
      if (!mask) break;
      __builtin_amdgcn_s_sleep(1);
      if (++guard > 4096) break;   // protocol-failure escape (no hang)
    }
    #pragma unroll
    for (int q = 0; q < 4; ++q) hv[q] = __uint_as_float(v[q]);

    // ---- stage to LDS (one ds_write_b128), single barrier per step ----
    *(float4*)&hs[par][4 * tid] = make_float4(hv[0], hv[1], hv[2], hv[3]);
    __syncthreads();  // B: hs[par] fully staged; wys[par^1] stable

    // ---- drain y_{t-2} (wys[par^1] written during step t-1) ----
    if (t >= 2 && wg == 0 && tid == 0)
      out[t - 2] = wys[par ^ 1][0] + wys[par ^ 1][1] + wys[par ^ 1][2] +
                   wys[par ^ 1][3] + wys[par ^ 1][4] + wys[par ^ 1][5] +
                   wys[par ^ 1][6] + wys[par ^ 1][7] + bout;

    // ---- z = W_hh @ h (per-lane partials over 32 columns) ----
    float acc[4] = {0.f, 0.f, 0.f, 0.f};
    #pragma unroll
    for (int j = 0; j < 8; ++j) {
      const float4 h4 = *(const float4*)&hs[par][j * 256 + lane * 4];
      #pragma unroll
      for (int g = 0; g < 4; ++g) {
        const float4 w = W[g * 8 + j];
        acc[g] = fmaf(w.x, h4.x, acc[g]);
        acc[g] = fmaf(w.y, h4.y, acc[g]);
        acc[g] = fmaf(w.z, h4.z, acc[g]);
        acc[g] = fmaf(w.w, h4.w, acc[g]);
      }
    }
    // ---- 64-lane butterfly: all lanes end with full row sums ----
    #pragma unroll
    for (int off = 32; off >= 1; off >>= 1) {
      #pragma unroll
      for (int g = 0; g < 4; ++g)
        acc[g] += __shfl_xor(acc[g], off, 64);
    }

    const float xt = xs[t];
    float z[4];
    #pragma unroll
    for (int g = 0; g < 4; ++g) z[g] = fmaf(xt, wx[g], acc[g] + bb[g]);

    // ---- gates (lane-redundant, identical values) ----
    const float gi = sigmoidf_(z[0]), gf = sigmoidf_(z[1]);
    const float gg = tanh_(z[2]), go = sigmoidf_(z[3]);
    cc = gf * cc + gi * gg;
    hh = go * tanh_(cc);

    // ---- publish h_t: fp32 with tag (t+1)&0xFF in low mantissa bits ----
    if (lane == 0) {
      const unsigned bits = (__float_as_uint(hh) & ~0xFFu) |
                            (((unsigned)(t + 1)) & 0xFFu);
      __hip_atomic_store(&hval[par * HDIM + k], bits, __ATOMIC_RELAXED,
                         __HIP_MEMORY_SCOPE_AGENT);
    }

    // ---- off-path: y_{t-1} partial from hv (h_{t-1}) ----
    float sy = 0.f;
    #pragma unroll
    for (int q = 0; q < 4; ++q) sy = fmaf(wo[q], hv[q], sy);
    #pragma unroll
    for (int off = 32; off >= 1; off >>= 1) sy += __shfl_xor(sy, off, 64);
    if (lane == 0) wys[par][wave] = sy;
  }

  // ---- epilogue ----
  __syncthreads();  // wys[(SEQ-1)&1] = wys[1] complete
  if (wg == 0 && tid == 0)
    out[SEQ - 2] = wys[1][0] + wys[1][1] + wys[1][2] + wys[1][3] + wys[1][4] +
                   wys[1][5] + wys[1][6] + wys[1][7] + bout;

  if (wg == 0) {
    // poll h_{SEQ-1}: slot (SEQ-1)&1 = 1, tag = SEQ&0xFF = 0
    const unsigned want = ((unsigned)SEQ) & 0xFFu;
    const unsigned* src = hval + HDIM + 4 * tid;
    unsigned v[4];
    unsigned mask = 0xFu;
    int guard = 0;
    for (;;) {
      #pragma unroll
      for (int q = 0; q < 4; ++q)
        if (mask & (1u << q))
          v[q] = __hip_atomic_load(&src[q], __ATOMIC_RELAXED,
                                   __HIP_MEMORY_SCOPE_AGENT);
      #pragma unroll
      for (int q = 0; q < 4; ++q)
        if ((mask & (1u << q)) && (v[q] & 0xFFu) == want)
          mask &= ~(1u << q);
      if (!mask) break;
      __builtin_amdgcn_s_sleep(1);
      if (++guard > 4096) break;
    }
    float sy = 0.f;
    #pragma unroll
    for (int q = 0; q < 4; ++q)
      sy = fmaf(wo[q], __uint_as_float(v[q]), sy);
    #pragma unroll
    for (int off = 32; off >= 1; off >>= 1) sy += __shfl_xor(sy, off, 64);
    if (lane == 0) wys[0][wave] = sy;
    __syncthreads();
    if (tid == 0)
      out[SEQ - 1] = wys[0][0] + wys[0][1] + wys[0][2] + wys[0][3] +
                     wys[0][4] + wys[0][5] + wys[0][6] + wys[0][7] + bout;
  }

  // ---- final h, c (exact local fp32 state) ----
  if (lane == 0) {
    out[SEQ + k] = hh;
    out[SEQ + HDIM + k] = cc;
  }
}

extern "C" void kernel_launch(void* const* d_in, const int* in_sizes, int n_in,
                              void* d_out, int out_size, void* d_ws, size_t ws_size,
                              hipStream_t stream) {
  const float* x     = (const float*)d_in[0];
  const float* w_ih  = (const float*)d_in[1];
  const float* w_hh  = (const float*)d_in[2];
  const float* b_ih  = (const float*)d_in[3];
  const float* b_hh  = (const float*)d_in[4];
  const float* w_out = (const float*)d_in[5];
  const float* b_out = (const float*)d_in[6];
  float* out = (float*)d_out;

  // ws layout: [0, 16KB): hval[2][2048] tagged fp32
  unsigned* hval = (unsigned*)d_ws;

  lstm_init<<<8, 256, 0, stream>>>(hval);
  lstm_persist<<<NWG, TPB, 0, stream>>>(x, w_ih, w_hh, b_ih, b_hh, w_out,
                                        b_out, out, hval);
}